// Round 14
// baseline (430.167 us; speedup 1.0000x reference)
//
#include <hip/hip_runtime.h>

#define CC 32
#define HH 256
#define WW 512
#define DD 64
#define PAD 64
#define RPITCH (WW + PAD)   // 576 words per padded r row (576%64==0: swizzle-safe)
#define CHUNK 4             // channels per LDS pass
#define NCHUNK (CC / CHUNK) // 8

// bank-balance swizzle: fold word-bit5 into float4-slot bit2.
// involution; constant over any 4-aligned float4 group -> b128 stays b128.
__device__ __forceinline__ int swz(int y) { return y ^ (((y >> 5) & 1) << 2); }

__global__ __launch_bounds__(256, 3) void cost_volume_kernel(
    const float* __restrict__ L, const float* __restrict__ R, float* __restrict__ O)
{
    // double-buffered: 2 x (8 KiB l + 9 KiB r) = 34 KiB -> 3 blocks/CU
    __shared__ float lA[2][CHUNK * WW];
    __shared__ float rB[2][CHUNK * RPITCH];

    const int tid = threadIdx.x;
    const int row = blockIdx.x;          // n*H + h
    const int n = row >> 8;
    const int h = row & 255;
    const size_t inbase = (size_t)n * (CC * HH * WW) + (size_t)h * WW;

    // zero the 64-word left pad of each r row in BOTH buffers, once;
    // staging never touches words [0,PAD) of a row, so pads stay zero.
    if (tid < 2 * CHUNK * 16) {
        const int b = tid >> 6, c = (tid >> 4) & 3, q = tid & 15;
        *reinterpret_cast<float4*>(&rB[b][c * RPITCH + swz(q * 4)]) =
            make_float4(0.f, 0.f, 0.f, 0.f);
    }

    // thread tile: 16 disparities x 8 widths. 4 waves x 64 lanes = 64d x 512w.
    const int wave = tid >> 6, lane = tid & 63;
    const int d0 = wave * 16;
    const int w0 = lane * 8;
    const int rbase = PAD + w0 - d0 - 16;   // 4-aligned, in [0,552]

    // precomputed swizzled read offsets (thread-constant; c-term is bit6+ only)
    const int loffA = swz(w0);
    const int loffB = swz(w0 + 4);
    int roff[6];
    #pragma unroll
    for (int k = 0; k < 6; ++k) roff[k] = swz(rbase + 4 * k);

    float acc[16][8];
    #pragma unroll
    for (int dd = 0; dd < 16; ++dd)
        #pragma unroll
        for (int j = 0; j < 8; ++j) acc[dd][j] = 0.f;

    // T14 reg-prefetch. Staging map: 4 rows x 128 float4 = 2 rounds x 256 thr.
    float4 lr0, lr1, rr0, rr1;
    const int c_0 = (tid      ) >> 7, q_0 = (tid      ) & 127;
    const int c_1 = (tid + 256) >> 7, q_1 = (tid + 256) & 127;
    const int wl0 = swz(q_0 * 4),       wl1 = swz(q_1 * 4);
    const int wr0 = swz(PAD + q_0 * 4), wr1 = swz(PAD + q_1 * 4);

    auto ld = [&](int ch) {
        const int c0 = ch * CHUNK;
        const size_t g0 = inbase + (size_t)(c0 + c_0) * (HH * WW);
        const size_t g1 = inbase + (size_t)(c0 + c_1) * (HH * WW);
        lr0 = reinterpret_cast<const float4*>(L + g0)[q_0];
        rr0 = reinterpret_cast<const float4*>(R + g0)[q_0];
        lr1 = reinterpret_cast<const float4*>(L + g1)[q_1];
        rr1 = reinterpret_cast<const float4*>(R + g1)[q_1];
    };
    auto wr = [&](int b) {
        *reinterpret_cast<float4*>(&lA[b][c_0 * WW + wl0]) = lr0;
        *reinterpret_cast<float4*>(&rB[b][c_0 * RPITCH + wr0]) = rr0;
        *reinterpret_cast<float4*>(&lA[b][c_1 * WW + wl1]) = lr1;
        *reinterpret_cast<float4*>(&rB[b][c_1 * RPITCH + wr1]) = rr1;
    };
    auto compute = [&](int b) {
        #pragma unroll
        for (int c = 0; c < CHUNK; ++c) {
            const float4 la = *reinterpret_cast<const float4*>(&lA[b][c * WW + loffA]);
            const float4 lb = *reinterpret_cast<const float4*>(&lA[b][c * WW + loffB]);
            float rwin[24];
            #pragma unroll
            for (int k = 0; k < 6; ++k) {
                const float4 rv = *reinterpret_cast<const float4*>(&rB[b][c * RPITCH + roff[k]]);
                rwin[k * 4 + 0] = rv.x; rwin[k * 4 + 1] = rv.y;
                rwin[k * 4 + 2] = rv.z; rwin[k * 4 + 3] = rv.w;
            }
            const float lvv[8] = {la.x, la.y, la.z, la.w, lb.x, lb.y, lb.z, lb.w};
            #pragma unroll
            for (int dd = 0; dd < 16; ++dd)
                #pragma unroll
                for (int j = 0; j < 8; ++j)
                    acc[dd][j] = fmaf(lvv[j], rwin[16 + j - dd], acc[dd][j]);
        }
    };

    // prologue: data(0) -> buf0; regs <- data(1); one barrier.
    ld(0);
    wr(0);
    ld(1);
    __syncthreads();   // pads + buf0 visible

    // single barrier per chunk; ld(ch+2) issued a full compute phase before
    // the barrier's vmcnt(0) drain -> HBM latency hidden under compute.
    // unroll 1: prevent cross-iteration software pipelining (R13: VGPR 256,
    // 140 MB spill). Buffer select is a runtime LDS address, costless.
    #pragma unroll 1
    for (int ch = 0; ch < NCHUNK; ++ch) {
        if (ch + 1 < NCHUNK) wr((ch + 1) & 1);
        if (ch + 2 < NCHUNK) ld(ch + 2);
        compute(ch & 1);
        __syncthreads();
    }

    const float inv = 1.0f / 32.0f;
    const size_t obase = (size_t)n * ((size_t)DD * HH * WW) + (size_t)h * WW + w0;
    #pragma unroll
    for (int dd = 0; dd < 16; ++dd) {
        const size_t ob = obase + (size_t)(d0 + dd) * (HH * WW);
        float4 o1, o2;
        o1.x = acc[dd][0] * inv; o1.y = acc[dd][1] * inv;
        o1.z = acc[dd][2] * inv; o1.w = acc[dd][3] * inv;
        o2.x = acc[dd][4] * inv; o2.y = acc[dd][5] * inv;
        o2.z = acc[dd][6] * inv; o2.w = acc[dd][7] * inv;
        *reinterpret_cast<float4*>(&O[ob]) = o1;
        *reinterpret_cast<float4*>(&O[ob + 4]) = o2;
    }
}

extern "C" void kernel_launch(void* const* d_in, const int* in_sizes, int n_in,
                              void* d_out, int out_size, void* d_ws, size_t ws_size,
                              hipStream_t stream) {
    const float* L = (const float*)d_in[0];
    const float* R = (const float*)d_in[1];
    float* O = (float*)d_out;
    cost_volume_kernel<<<8 * HH, 256, 0, stream>>>(L, R, O);
}

// Round 15
// 125.653 us; speedup vs baseline: 3.4234x; 3.4234x over previous
//
#include <hip/hip_runtime.h>

#define CC 32
#define HH 256
#define WW 512
#define DD 64
#define PAD 64
#define RPITCH (WW + PAD)   // 576 words per padded r row (576%64==0: swizzle-safe)
#define CHUNK 4             // channels per LDS pass
#define NCHUNK (CC / CHUNK) // 8

// bank-balance swizzle: fold word-bit5 into float4-slot bit2.
// involution; constant over any 4-aligned float4 group -> b128 stays b128.
__device__ __forceinline__ int swz(int y) { return y ^ (((y >> 5) & 1) << 2); }

__global__ __launch_bounds__(256) void cost_volume_kernel(
    const float* __restrict__ L, const float* __restrict__ R, float* __restrict__ O)
{
    // double-buffered: 2 x (8 KiB l + 9 KiB r) = 34 KiB
    __shared__ float lA[2][CHUNK * WW];
    __shared__ float rB[2][CHUNK * RPITCH];

    const int tid = threadIdx.x;
    const int row = blockIdx.x;          // n*H + h
    const int n = row >> 8;
    const int h = row & 255;
    const size_t inbase = (size_t)n * (CC * HH * WW) + (size_t)h * WW;

    // zero the 64-word left pad of each r row in BOTH buffers, once;
    // staging never touches words [0,PAD) of a row, so pads stay zero.
    if (tid < 2 * CHUNK * 16) {
        const int b = tid >> 6, c = (tid >> 4) & 3, q = tid & 15;
        *reinterpret_cast<float4*>(&rB[b][c * RPITCH + swz(q * 4)]) =
            make_float4(0.f, 0.f, 0.f, 0.f);
    }

    // thread tile: 16 disparities x 8 widths. 4 waves x 64 lanes = 64d x 512w.
    const int wave = tid >> 6, lane = tid & 63;
    const int d0 = wave * 16;
    const int w0 = lane * 8;
    const int rbase = PAD + w0 - d0 - 16;   // 4-aligned, in [0,552]

    // precomputed swizzled read offsets (thread-constant; c-term is bit6+ only)
    const int loffA = swz(w0);
    const int loffB = swz(w0 + 4);
    int roff[6];
    #pragma unroll
    for (int k = 0; k < 6; ++k) roff[k] = swz(rbase + 4 * k);

    float acc[16][8];
    #pragma unroll
    for (int dd = 0; dd < 16; ++dd)
        #pragma unroll
        for (int j = 0; j < 8; ++j) acc[dd][j] = 0.f;

    // T14 reg-prefetch. Staging map: 4 rows x 128 float4 = 2 rounds x 256 thr.
    float4 lr0, lr1, rr0, rr1;
    const int c_0 = (tid      ) >> 7, q_0 = (tid      ) & 127;
    const int c_1 = (tid + 256) >> 7, q_1 = (tid + 256) & 127;
    const int wl0 = swz(q_0 * 4),       wl1 = swz(q_1 * 4);
    const int wr0 = swz(PAD + q_0 * 4), wr1 = swz(PAD + q_1 * 4);

    auto ld = [&](int ch) {
        const int c0 = ch * CHUNK;
        const size_t g0 = inbase + (size_t)(c0 + c_0) * (HH * WW);
        const size_t g1 = inbase + (size_t)(c0 + c_1) * (HH * WW);
        lr0 = reinterpret_cast<const float4*>(L + g0)[q_0];
        rr0 = reinterpret_cast<const float4*>(R + g0)[q_0];
        lr1 = reinterpret_cast<const float4*>(L + g1)[q_1];
        rr1 = reinterpret_cast<const float4*>(R + g1)[q_1];
    };
    auto wr = [&](int b) {
        *reinterpret_cast<float4*>(&lA[b][c_0 * WW + wl0]) = lr0;
        *reinterpret_cast<float4*>(&rB[b][c_0 * RPITCH + wr0]) = rr0;
        *reinterpret_cast<float4*>(&lA[b][c_1 * WW + wl1]) = lr1;
        *reinterpret_cast<float4*>(&rB[b][c_1 * RPITCH + wr1]) = rr1;
    };
    auto compute = [&](int b) {
        #pragma unroll
        for (int c = 0; c < CHUNK; ++c) {
            const float4 la = *reinterpret_cast<const float4*>(&lA[b][c * WW + loffA]);
            const float4 lb = *reinterpret_cast<const float4*>(&lA[b][c * WW + loffB]);
            float rwin[24];
            #pragma unroll
            for (int k = 0; k < 6; ++k) {
                const float4 rv = *reinterpret_cast<const float4*>(&rB[b][c * RPITCH + roff[k]]);
                rwin[k * 4 + 0] = rv.x; rwin[k * 4 + 1] = rv.y;
                rwin[k * 4 + 2] = rv.z; rwin[k * 4 + 3] = rv.w;
            }
            const float lvv[8] = {la.x, la.y, la.z, la.w, lb.x, lb.y, lb.z, lb.w};
            #pragma unroll
            for (int dd = 0; dd < 16; ++dd)
                #pragma unroll
                for (int j = 0; j < 8; ++j)
                    acc[dd][j] = fmaf(lvv[j], rwin[16 + j - dd], acc[dd][j]);
        }
    };

    // prologue: data(0) -> buf0; regs <- data(1); one barrier.
    ld(0);
    wr(0);
    ld(1);
    __syncthreads();   // pads + buf0 visible

    // single barrier per chunk; ld(ch+2) issued a full compute phase before
    // the barrier's vmcnt(0) drain -> HBM latency hidden under compute.
    // unroll 1: prevent cross-iteration software pipelining (R13: VGPR 256,
    // 140 MB spill). NO launch_bounds min-waves arg (R6/R14: cap ~ 512/(2w),
    // drove acc itself to scratch).
    #pragma unroll 1
    for (int ch = 0; ch < NCHUNK; ++ch) {
        if (ch + 1 < NCHUNK) wr((ch + 1) & 1);
        if (ch + 2 < NCHUNK) ld(ch + 2);
        compute(ch & 1);
        __syncthreads();
    }

    const float inv = 1.0f / 32.0f;
    const size_t obase = (size_t)n * ((size_t)DD * HH * WW) + (size_t)h * WW + w0;
    #pragma unroll
    for (int dd = 0; dd < 16; ++dd) {
        const size_t ob = obase + (size_t)(d0 + dd) * (HH * WW);
        float4 o1, o2;
        o1.x = acc[dd][0] * inv; o1.y = acc[dd][1] * inv;
        o1.z = acc[dd][2] * inv; o1.w = acc[dd][3] * inv;
        o2.x = acc[dd][4] * inv; o2.y = acc[dd][5] * inv;
        o2.z = acc[dd][6] * inv; o2.w = acc[dd][7] * inv;
        *reinterpret_cast<float4*>(&O[ob]) = o1;
        *reinterpret_cast<float4*>(&O[ob + 4]) = o2;
    }
}

extern "C" void kernel_launch(void* const* d_in, const int* in_sizes, int n_in,
                              void* d_out, int out_size, void* d_ws, size_t ws_size,
                              hipStream_t stream) {
    const float* L = (const float*)d_in[0];
    const float* R = (const float*)d_in[1];
    float* O = (float*)d_out;
    cost_volume_kernel<<<8 * HH, 256, 0, stream>>>(L, R, O);
}